// Round 6
// baseline (9791.323 us; speedup 1.0000x reference)
//
#include <hip/hip_runtime.h>

#define T_STEPS 31
#define CIN     64
#define COUT    512
#define WSLEN   512
#define KSZ     32
#define CSTRIDE 16
#define KRED    2048                 // CIN*KSZ
#define NBATCH  1024
#define BCHUNK  512                  // batch rows per pass (seq buffer reuse)
#define MCHUNK  (BCHUNK * T_STEPS)   // 15872 rows per pass

__device__ __forceinline__ double clip01d(double v) { return fmin(fmax(v, 0.0), 1.0); }

// ---------------------------------------------------------------------------
// Prep: transpose conv_w [co][ci][k] -> wT [r=ci*32+k][co]   (f32, exact)
//       transpose fc1_w  [co][c]     -> fc1wT [c][co]        (f32, exact)
// ---------------------------------------------------------------------------
__global__ __launch_bounds__(256) void prep_kernel(
    const float* __restrict__ conv_w, const float* __restrict__ fc1_w,
    float* __restrict__ wT, float* __restrict__ fc1wT)
{
    int idx = blockIdx.x * 256 + threadIdx.x;
    int co = idx & 511;
    int r  = idx >> 9;
    if (idx < KRED * COUT)  wT[idx]    = conv_w[co * KRED + r];
    if (idx < COUT * COUT)  fc1wT[idx] = fc1_w[co * COUT + r];
}

// ---------------------------------------------------------------------------
// Conv1d + BN f64 v3 (chunk 0 — treatment): BM=BN=128, BK=8, 8x8 micro-tile.
// 64 f64 FMA per thread per kk -> 4x FMA-per-LDS-byte vs v2. Conflict-free
// B cols {tx+16c}, broadcast A rows {ty*8+i}. Double-buffered, 1 barrier/tile.
// ---------------------------------------------------------------------------
__global__ __launch_bounds__(256, 2) void conv_bn_f64_v3_kernel(
    const float* __restrict__ x, const float* __restrict__ wT,
    const float* __restrict__ conv_b,
    const float* __restrict__ bn_gamma, const float* __restrict__ bn_beta,
    const float* __restrict__ bn_mean,  const float* __restrict__ bn_var,
    double* __restrict__ seq, int b_base)
{
    __shared__ double As[2][8][128];   // [buf][k][m]  16 KB
    __shared__ double Bs[2][8][128];   // [buf][k][n]  16 KB

    const int tid = threadIdx.x;
    const int nMB = MCHUNK / 128;          // 124
    const int bm  = blockIdx.x % nMB;
    const int bnk = blockIdx.x / nMB;
    const int m0 = bm * 128, n0 = bnk * 128;

    // A staging: row miA = tid&127, k-half khA = (tid>>7)*4
    const int miA = tid & 127;
    const int khA = (tid >> 7) * 4;
    const int mA  = m0 + miA;
    const int bA  = b_base + mA / T_STEPS;
    const int tA  = mA % T_STEPS;
    const float* xp = x + (size_t)bA * CIN * WSLEN + tA * CSTRIDE;

    // B staging: k-row krB = tid>>5 (0..7), col quad nqB = tid&31
    const int krB = tid >> 5;
    const int nqB = tid & 31;

    // micro-tile: rows ty*8+{0..7}, cols tx+{0,16,...,112}
    const int tx = tid & 15, ty = tid >> 4;

    double acc[8][8] = {};                 // [row i][col group c]

    // ---- prologue: stage tile 0 (kt=0: ci=0, ks=0) ----
    {
        float4 a = *(const float4*)(xp + khA);
        float4 b = *(const float4*)(wT + (size_t)krB * COUT + n0 + nqB * 4);
        As[0][khA + 0][miA] = (double)a.x;
        As[0][khA + 1][miA] = (double)a.y;
        As[0][khA + 2][miA] = (double)a.z;
        As[0][khA + 3][miA] = (double)a.w;
        Bs[0][krB][nqB * 4 + 0] = (double)b.x;
        Bs[0][krB][nqB * 4 + 1] = (double)b.y;
        Bs[0][krB][nqB * 4 + 2] = (double)b.z;
        Bs[0][krB][nqB * 4 + 3] = (double)b.w;
    }
    __syncthreads();

    const int NT = KRED / 8;               // 256 K-tiles
    for (int it = 0; it < NT; ++it) {
        const int cur = it & 1;

        float4 a2, b2;
        const bool more = (it + 1 < NT);
        if (more) {
            const int kt = (it + 1) * 8;
            a2 = *(const float4*)(xp + (kt >> 5) * WSLEN + (kt & 31) + khA);
            b2 = *(const float4*)(wT + (size_t)(kt + krB) * COUT + n0 + nqB * 4);
        }

        #pragma unroll
        for (int kk = 0; kk < 8; ++kk) {
            double a_[8], b_[8];
            *(double2*)&a_[0] = *(const double2*)&As[cur][kk][ty * 8 + 0];
            *(double2*)&a_[2] = *(const double2*)&As[cur][kk][ty * 8 + 2];
            *(double2*)&a_[4] = *(const double2*)&As[cur][kk][ty * 8 + 4];
            *(double2*)&a_[6] = *(const double2*)&As[cur][kk][ty * 8 + 6];
            #pragma unroll
            for (int c = 0; c < 8; ++c) b_[c] = Bs[cur][kk][tx + 16 * c];
            #pragma unroll
            for (int i = 0; i < 8; ++i)
                #pragma unroll
                for (int c = 0; c < 8; ++c)
                    acc[i][c] = fma(a_[i], b_[c], acc[i][c]);
        }

        if (more) {
            const int nxt = cur ^ 1;
            As[nxt][khA + 0][miA] = (double)a2.x;
            As[nxt][khA + 1][miA] = (double)a2.y;
            As[nxt][khA + 2][miA] = (double)a2.z;
            As[nxt][khA + 3][miA] = (double)a2.w;
            Bs[nxt][krB][nqB * 4 + 0] = (double)b2.x;
            Bs[nxt][krB][nqB * 4 + 1] = (double)b2.y;
            Bs[nxt][krB][nqB * 4 + 2] = (double)b2.z;
            Bs[nxt][krB][nqB * 4 + 3] = (double)b2.w;
        }
        __syncthreads();
    }

    // ---- epilogue: conv bias + BN in f64, store double ----
    #pragma unroll
    for (int c = 0; c < 8; ++c) {
        const int n = n0 + tx + 16 * c;
        double g  = (double)bn_gamma[n];
        double be = (double)bn_beta[n];
        double mn = (double)bn_mean[n];
        double vr = (double)bn_var[n];
        double cb = (double)conv_b[n];
        double inv = 1.0 / sqrt(vr + 1e-5);
        #pragma unroll
        for (int i = 0; i < 8; ++i) {
            int m = m0 + ty * 8 + i;
            seq[(size_t)m * COUT + n] = g * (acc[i][c] + cb - mn) * inv + be;
        }
    }
}

// ---------------------------------------------------------------------------
// Conv1d + BN f64 v2 (chunk 1 — R5 control, unchanged).
// ---------------------------------------------------------------------------
__global__ __launch_bounds__(256) void conv_bn_f64_v2_kernel(
    const float* __restrict__ x, const float* __restrict__ wT,
    const float* __restrict__ conv_b,
    const float* __restrict__ bn_gamma, const float* __restrict__ bn_beta,
    const float* __restrict__ bn_mean,  const float* __restrict__ bn_var,
    double* __restrict__ seq, int b_base)
{
    __shared__ double As[2][16][64];
    __shared__ double Bs[2][16][64];

    const int tid = threadIdx.x;
    const int nMB = MCHUNK / 64;           // 248
    const int bm = blockIdx.x % nMB;
    const int bn = blockIdx.x / nMB;
    const int m0 = bm * 64, n0 = bn * 64;

    const int miA = tid & 63;
    const int kqA = tid >> 6;
    const int mA  = m0 + miA;
    const int bA  = b_base + mA / T_STEPS;
    const int tA  = mA % T_STEPS;
    const float* xp = x + (size_t)bA * CIN * WSLEN + tA * CSTRIDE;
    const int rB  = tid >> 4;
    const int nqB = tid & 15;

    const int tx = tid & 15, ty = tid >> 4;

    double acc[4][4] = {};

    {
        float4 a = *(const float4*)(xp + kqA * 4);
        float4 b = *(const float4*)(wT + (size_t)rB * COUT + n0 + nqB * 4);
        As[0][kqA * 4 + 0][miA] = (double)a.x;
        As[0][kqA * 4 + 1][miA] = (double)a.y;
        As[0][kqA * 4 + 2][miA] = (double)a.z;
        As[0][kqA * 4 + 3][miA] = (double)a.w;
        Bs[0][rB][nqB * 4 + 0] = (double)b.x;
        Bs[0][rB][nqB * 4 + 1] = (double)b.y;
        Bs[0][rB][nqB * 4 + 2] = (double)b.z;
        Bs[0][rB][nqB * 4 + 3] = (double)b.w;
    }
    __syncthreads();

    const int NKT16 = KRED / 16;           // 128
    for (int it = 0; it < NKT16; ++it) {
        const int cur = it & 1;
        float4 a2, b2;
        const bool more = (it + 1 < NKT16);
        if (more) {
            const int kt = (it + 1) * 16;
            a2 = *(const float4*)(xp + (kt >> 5) * WSLEN + (kt & 31) + kqA * 4);
            b2 = *(const float4*)(wT + (size_t)(kt + rB) * COUT + n0 + nqB * 4);
        }
        #pragma unroll
        for (int kk = 0; kk < 16; ++kk) {
            double av[4];
            *(double2*)&av[0] = *(const double2*)&As[cur][kk][ty * 4 + 0];
            *(double2*)&av[2] = *(const double2*)&As[cur][kk][ty * 4 + 2];
            double bv0 = Bs[cur][kk][tx];
            double bv1 = Bs[cur][kk][tx + 16];
            double bv2 = Bs[cur][kk][tx + 32];
            double bv3 = Bs[cur][kk][tx + 48];
            #pragma unroll
            for (int i = 0; i < 4; ++i) {
                acc[i][0] = fma(av[i], bv0, acc[i][0]);
                acc[i][1] = fma(av[i], bv1, acc[i][1]);
                acc[i][2] = fma(av[i], bv2, acc[i][2]);
                acc[i][3] = fma(av[i], bv3, acc[i][3]);
            }
        }
        if (more) {
            const int nxt = cur ^ 1;
            As[nxt][kqA * 4 + 0][miA] = (double)a2.x;
            As[nxt][kqA * 4 + 1][miA] = (double)a2.y;
            As[nxt][kqA * 4 + 2][miA] = (double)a2.z;
            As[nxt][kqA * 4 + 3][miA] = (double)a2.w;
            Bs[nxt][rB][nqB * 4 + 0] = (double)b2.x;
            Bs[nxt][rB][nqB * 4 + 1] = (double)b2.y;
            Bs[nxt][rB][nqB * 4 + 2] = (double)b2.z;
            Bs[nxt][rB][nqB * 4 + 3] = (double)b2.w;
        }
        __syncthreads();
    }

    #pragma unroll
    for (int c = 0; c < 4; ++c) {
        const int n = n0 + tx + 16 * c;
        double g  = (double)bn_gamma[n];
        double be = (double)bn_beta[n];
        double mn = (double)bn_mean[n];
        double vr = (double)bn_var[n];
        double cb = (double)conv_b[n];
        double inv = 1.0 / sqrt(vr + 1e-5);
        #pragma unroll
        for (int i = 0; i < 4; ++i) {
            int m = m0 + ty * 4 + i;
            seq[(size_t)m * COUT + n] = g * (acc[i][c] + cb - mn) * inv + be;
        }
    }
}

// ---------------------------------------------------------------------------
// SNN scan v3 (unchanged): 1 batch row per block, 512 threads.
// ---------------------------------------------------------------------------
__global__ __launch_bounds__(512, 4) void snn_scan_v3_kernel(
    const double* __restrict__ seq, const float* __restrict__ fc1wT,
    const float* __restrict__ fc1_b, const float* __restrict__ fc2_w,
    const float* __restrict__ fc2_b, const float* __restrict__ beta_enc,
    const float* __restrict__ beta_hid, const float* __restrict__ beta_out,
    float* __restrict__ out, int b_base)
{
    __shared__ int   list[COUT];
    __shared__ int   wcnt[8];
    __shared__ double red[8][2];

    const int tid  = threadIdx.x;
    const int lane = tid & 63;
    const int wave = tid >> 6;
    const int row  = blockIdx.x;
    const int brow = b_base + row;

    const double be  = clip01d((double)beta_enc[tid]);
    const double bh  = clip01d((double)beta_hid[tid]);
    const double f1b = (double)fc1_b[tid];
    const double w2a = (double)fc2_w[tid];
    const double w2b = (double)fc2_w[COUT + tid];

    double bo = 0.0, f2b = 0.0, om = 0.0;
    if (tid < 2) { bo = clip01d((double)beta_out[tid]); f2b = (double)fc2_b[tid]; }

    double em = 0.0, hm = 0.0;
    const double* sp = seq + (size_t)row * T_STEPS * COUT + tid;

    for (int t = 0; t < T_STEPS; ++t) {
        double inp = sp[(size_t)t * COUT];
        double e = be * em + inp - ((em > 1.0) ? 1.0 : 0.0);
        em = e;
        bool spike = (e > 1.0);

        unsigned long long mask = __ballot(spike);
        if (lane == 0) wcnt[wave] = __popcll(mask);
        __syncthreads();

        int base = 0, cnt = 0;
        #pragma unroll
        for (int w = 0; w < 8; ++w) {
            int v = wcnt[w];
            base += (w < wave) ? v : 0;
            cnt  += v;
        }
        if (spike) {
            int pos = base + __popcll(mask & ((1ull << lane) - 1ull));
            list[pos] = tid;
        }
        __syncthreads();

        double s0 = 0.0, s1 = 0.0, s2 = 0.0, s3 = 0.0;
        const float* fw = fc1wT + tid;
        int i = 0;
        for (; i + 4 <= cnt; i += 4) {
            int cA = list[i], cB = list[i + 1], cC = list[i + 2], cD = list[i + 3];
            float wA = fw[(size_t)cA * COUT];
            float wB = fw[(size_t)cB * COUT];
            float wC = fw[(size_t)cC * COUT];
            float wD = fw[(size_t)cD * COUT];
            s0 += (double)wA;
            s1 += (double)wB;
            s2 += (double)wC;
            s3 += (double)wD;
        }
        for (; i < cnt; ++i) s0 += (double)fw[(size_t)list[i] * COUT];
        double cur1 = ((s0 + s1) + (s2 + s3)) + f1b;

        double h = bh * hm + cur1 - ((hm > 1.0) ? 1.0 : 0.0);
        hm = h;
        double sh = (h > 1.0) ? 1.0 : 0.0;
        double p0 = sh * w2a;
        double p1 = sh * w2b;
        #pragma unroll
        for (int off = 32; off > 0; off >>= 1) {
            p0 += __shfl_down(p0, off);
            p1 += __shfl_down(p1, off);
        }
        if (lane == 0) { red[wave][0] = p0; red[wave][1] = p1; }
        __syncthreads();

        if (tid < 2) {
            double cur2 = f2b;
            #pragma unroll
            for (int w = 0; w < 8; ++w) cur2 += red[w][tid];
            double o = bo * om + cur2 - ((om > 1.0) ? 1.0 : 0.0);
            om = o;
            float so = (o > 1.0) ? 1.0f : 0.0f;
            int bidx = brow * 2 + tid;
            out[2048 + t * 2048 + bidx] = so;               // spk_rec
            out[2048 + 63488 + t * 2048 + bidx] = (float)o; // mem_rec
            if (t == T_STEPS - 1) out[bidx] = (float)o;     // final om
        }
    }
}

// ---------------------------------------------------------------------------
extern "C" void kernel_launch(void* const* d_in, const int* in_sizes, int n_in,
                              void* d_out, int out_size, void* d_ws, size_t ws_size,
                              hipStream_t stream)
{
    const float* x        = (const float*)d_in[0];
    const float* conv_w   = (const float*)d_in[1];
    const float* conv_b   = (const float*)d_in[2];
    const float* bn_gamma = (const float*)d_in[3];
    const float* bn_beta  = (const float*)d_in[4];
    const float* bn_mean  = (const float*)d_in[5];
    const float* bn_var   = (const float*)d_in[6];
    const float* fc1_w    = (const float*)d_in[7];
    const float* fc1_b    = (const float*)d_in[8];
    const float* fc2_w    = (const float*)d_in[9];
    const float* fc2_b    = (const float*)d_in[10];
    const float* beta_enc = (const float*)d_in[11];
    const float* beta_hid = (const float*)d_in[12];
    const float* beta_out = (const float*)d_in[13];
    float* out = (float*)d_out;

    float*  wT    = (float*)d_ws;                       // [2048][512] f32, 4 MB
    float*  fc1wT = wT + (size_t)KRED * COUT;           // [512][512]  f32, 1 MB
    double* seq   = (double*)(fc1wT + (size_t)COUT * COUT); // [15872][512] f64, 65 MB

    prep_kernel<<<4096, 256, 0, stream>>>(conv_w, fc1_w, wT, fc1wT);

    // chunk 0: v3 treatment (128x128 tile, 8x8 micro)
    conv_bn_f64_v3_kernel<<<(MCHUNK / 128) * (COUT / 128), 256, 0, stream>>>(
        x, wT, conv_b, bn_gamma, bn_beta, bn_mean, bn_var, seq, 0);
    snn_scan_v3_kernel<<<BCHUNK, 512, 0, stream>>>(
        seq, fc1wT, fc1_b, fc2_w, fc2_b, beta_enc, beta_hid, beta_out, out, 0);

    // chunk 1: v2 control (R5 kernel)
    conv_bn_f64_v2_kernel<<<(MCHUNK / 64) * (COUT / 64), 256, 0, stream>>>(
        x, wT, conv_b, bn_gamma, bn_beta, bn_mean, bn_var, seq, BCHUNK);
    snn_scan_v3_kernel<<<BCHUNK, 512, 0, stream>>>(
        seq, fc1wT, fc1_b, fc2_w, fc2_b, beta_enc, beta_hid, beta_out, out, BCHUNK);
}

// Round 8
// 963.842 us; speedup vs baseline: 10.1586x; 10.1586x over previous
//
#include <hip/hip_runtime.h>

#define T_STEPS 31
#define CIN     64
#define COUT    512
#define WSLEN   512
#define CSTRIDE 16
#define KRED    2048                 // CIN*32
#define NBATCH  1024
#define BCHUNK  512                  // batch rows per pass (seq buffer reuse)
#define MCHUNK  (BCHUNK * T_STEPS)   // 15872 rows per pass

typedef int v4i __attribute__((ext_vector_type(4)));

__device__ __forceinline__ double clip01d(double v) { return fmin(fmax(v, 0.0), 1.0); }

// ---------------------------------------------------------------------------
// Digitize 4 pre-scaled floats (|v| < 0.75) into 5 base-128 digits each,
// packed one byte per element per plane. Exact: every rintf/fmaf result is
// exactly representable; digits d1..d5 reproduce all f32 mantissa bits for
// |v| >= 2^-8 (residual <= 2^-36 otherwise). Digit ranges within i8.
// ---------------------------------------------------------------------------
__device__ __forceinline__ void dig5(float4 f, unsigned int w[5]) {
    float vv[4] = {f.x, f.y, f.z, f.w};
    unsigned int w0 = 0, w1 = 0, w2 = 0, w3 = 0, w4 = 0;
    #pragma unroll
    for (int e = 0; e < 4; ++e) {
        float v  = vv[e];
        float c0 = rintf(v * 16384.0f);                     // d1*128+d2
        float r1 = fmaf(c0, -6.103515625e-05f, v);          // v - c0*2^-14
        float c1 = rintf(r1 * 268435456.0f);                // d3*128+d4
        float r2 = fmaf(c1, -3.725290298461914e-09f, r1);   // r1 - c1*2^-28
        float c2 = rintf(r2 * 34359738368.0f);              // d5 = r2*2^35
        int i0 = (int)c0, i1 = (int)c1, i2 = (int)c2;
        int d2 = ((i0 + 64) & 127) - 64;                    // balanced split
        int d1 = (i0 - d2) >> 7;
        int d4 = ((i1 + 64) & 127) - 64;
        int d3 = (i1 - d4) >> 7;
        w0 |= (unsigned int)(d1 & 255) << (8 * e);
        w1 |= (unsigned int)(d2 & 255) << (8 * e);
        w2 |= (unsigned int)(d3 & 255) << (8 * e);
        w3 |= (unsigned int)(d4 & 255) << (8 * e);
        w4 |= (unsigned int)(i2 & 255) << (8 * e);
    }
    w[0] = w0; w[1] = w1; w[2] = w2; w[3] = w3; w[4] = w4;
}

// ---------------------------------------------------------------------------
// Prep 1: transpose fc1_w [co][c] -> fc1wT [c][co]  (f32, exact)
// ---------------------------------------------------------------------------
__global__ __launch_bounds__(256) void prep_fc1_kernel(
    const float* __restrict__ fc1_w, float* __restrict__ fc1wT)
{
    int idx = blockIdx.x * 256 + threadIdx.x;      // 262144 threads
    int co = idx & 511;
    int r  = idx >> 9;
    fc1wT[idx] = fc1_w[co * COUT + r];
}

// ---------------------------------------------------------------------------
// Prep 2: digitize conv_w (scaled by 4 = 1/s_B) into 5 i8 digit planes in
// mfma_i32_16x16x64_i8 B-fragment order:
//   plane q (1 MB): block (kt=k>>6, ct=co>>4) of 1 KB; byte at
//   lane*16 + (k&15), lane = (co&15) + 16*((k>>4)&3).
// ---------------------------------------------------------------------------
__global__ __launch_bounds__(256) void prep_bd_kernel(
    const float* __restrict__ conv_w, signed char* __restrict__ Bd)
{
    int t  = blockIdx.x * 256 + threadIdx.x;       // 262144 threads
    int k4 = (t & 511) << 2;                       // 0..2044
    int co = t >> 9;                               // 0..511
    float4 w4 = *(const float4*)(conv_w + (size_t)co * KRED + k4);
    float4 v4 = make_float4(w4.x * 4.0f, w4.y * 4.0f, w4.z * 4.0f, w4.w * 4.0f);
    unsigned int pk[5];
    dig5(v4, pk);
    int off = (((k4 >> 6) * 32 + (co >> 4)) << 10)
            + ((co & 15) + ((k4 >> 4) & 3) * 16) * 16 + (k4 & 15);
    #pragma unroll
    for (int q = 0; q < 5; ++q)
        *(unsigned int*)(Bd + q * 1048576 + off) = pk[q];
}

// ---------------------------------------------------------------------------
// Conv1d + BN via exact i8-digit MFMA, 5 A-digits x 5 B-digits, all pairs
// p+q<=6 (15 MFMAs/subtile/kt). Pairs of equal p+q chain into ONE i32
// accumulator (same reconstruction weight; worst sum 4.5e7 << 2^31, exact).
// Block 64x64 (512 thr, 8 waves), wave = 16 rows x 32 cols (2 subtiles).
// A digitized on the fly into LDS fragment layout; B staged from Bd planes.
// Global loads software-pipelined one kt ahead. Reconstruction + BN in f64.
// ---------------------------------------------------------------------------
__global__ __launch_bounds__(512, 2) void conv_bn_i8v2_kernel(
    const float* __restrict__ x, const signed char* __restrict__ Bd,
    const float* __restrict__ conv_b,
    const float* __restrict__ bn_gamma, const float* __restrict__ bn_beta,
    const float* __restrict__ bn_mean,  const float* __restrict__ bn_var,
    double* __restrict__ seq, int b_base)
{
    __shared__ __align__(16) signed char Alds[5 * 4096];   // plane p: p*4096 + rg*1024
    __shared__ __align__(16) signed char Blds[5 * 4096];   // plane q: q*4096 + ct*1024

    const int tid = threadIdx.x;
    const int nMB = MCHUNK / 64;           // 248
    const int bm  = blockIdx.x % nMB;
    const int bnk = blockIdx.x / nMB;
    const int m0 = bm * 64, n0 = bnk * 64;

    // --- A digitize/staging map: thread -> (row rA, k-quad kqA, 8-byte half jqh)
    const int rA  = tid & 63;
    const int gA  = tid >> 6;
    const int kqA = gA & 3;
    const int jqh = gA >> 2;
    const int mA  = m0 + rA;
    const int bA  = b_base + mA / T_STEPS;
    const int tA  = mA % T_STEPS;
    const float* xp = x + (size_t)bA * CIN * WSLEN + tA * CSTRIDE;
    const int awb  = ((rA >> 4) << 10) + ((rA & 15) + kqA * 16) * 16 + jqh * 8;
    const int kloc = kqA * 16 + jqh * 8;   // k offset within the 64-wide tile

    // --- B staging map: 1280 16B-slots/kt; thread covers slots tid, tid+512,
    //     and (tid<256) slot 1024+tid. q = slot>>8, rem = slot&255.
    const int remB = tid & 255;
    const int qB0  = tid >> 8;             // 0/1
    const int qB1  = 2 + (tid >> 8);       // 2/3
    const size_t cbase = ((size_t)(bnk * 4) << 10);
    const signed char* Bq0 = Bd + (size_t)qB0 * 1048576 + cbase + remB * 16;
    const signed char* Bq1 = Bd + (size_t)qB1 * 1048576 + cbase + remB * 16;
    const signed char* Bq2 = Bd + (size_t)4   * 1048576 + cbase + tid  * 16;

    // --- MFMA map ---
    const int wv  = tid >> 6;
    const int l   = tid & 63;
    const int rgM = wv >> 1;               // row group 0..3
    const int cb2 = (wv & 1) * 2;          // col-tile base (2 subtiles)

    v4i acc[2][5];                         // [subtile][diagonal p+q-2]
    #pragma unroll
    for (int s = 0; s < 2; ++s)
        #pragma unroll
        for (int d = 0; d < 5; ++d) acc[s][d] = (v4i){0, 0, 0, 0};

    // ---- prologue: issue tile-0 global loads ----
    uint4 sb0, sb1, sb2;
    float4 sxa, sxb;
    sb0 = *(const uint4*)(Bq0);
    sb1 = *(const uint4*)(Bq1);
    if (tid < 256) sb2 = *(const uint4*)(Bq2);
    sxa = *(const float4*)(xp + (kloc >> 5) * WSLEN + (kloc & 31));
    sxb = *(const float4*)(xp + ((kloc + 4) >> 5) * WSLEN + ((kloc + 4) & 31));

    for (int kt = 0; kt < 32; ++kt) {
        // digitize A (s_A = 8)
        unsigned int pa[5], pb[5];
        dig5(make_float4(sxa.x * 0.125f, sxa.y * 0.125f, sxa.z * 0.125f, sxa.w * 0.125f), pa);
        dig5(make_float4(sxb.x * 0.125f, sxb.y * 0.125f, sxb.z * 0.125f, sxb.w * 0.125f), pb);

        __syncthreads();                   // previous fragment reads complete
        #pragma unroll
        for (int p = 0; p < 5; ++p)
            *(uint2*)(Alds + p * 4096 + awb) = make_uint2(pa[p], pb[p]);
        *(uint4*)(Blds + qB0 * 4096 + remB * 16) = sb0;
        *(uint4*)(Blds + qB1 * 4096 + remB * 16) = sb1;
        if (tid < 256) *(uint4*)(Blds + 4 * 4096 + tid * 16) = sb2;

        // issue next tile's global loads (regs consumed; latency hides under MFMA)
        if (kt + 1 < 32) {
            size_t ko = (size_t)(kt + 1) * 32768;
            sb0 = *(const uint4*)(Bq0 + ko);
            sb1 = *(const uint4*)(Bq1 + ko);
            if (tid < 256) sb2 = *(const uint4*)(Bq2 + ko);
            int gk = (kt + 1) * 64 + kloc;
            sxa = *(const float4*)(xp + (gk >> 5) * WSLEN + (gk & 31));
            sxb = *(const float4*)(xp + ((gk + 4) >> 5) * WSLEN + ((gk + 4) & 31));
        }
        __syncthreads();                   // staged data visible

        v4i aF[5], bF0[5], bF1[5];
        #pragma unroll
        for (int p = 0; p < 5; ++p)
            aF[p]  = *(const v4i*)(Alds + p * 4096 + (rgM << 10) + (l << 4));
        #pragma unroll
        for (int q = 0; q < 5; ++q) {
            bF0[q] = *(const v4i*)(Blds + q * 4096 + ((cb2 + 0) << 10) + (l << 4));
            bF1[q] = *(const v4i*)(Blds + q * 4096 + ((cb2 + 1) << 10) + (l << 4));
        }

        // diagonal-chained MFMAs: acc[s][d] += sum_{p+q=d} A_p * B_q
        #define MF(A_, B_, C_) __builtin_amdgcn_mfma_i32_16x16x64_i8(A_, B_, C_, 0, 0, 0)
        acc[0][0] = MF(aF[0], bF0[0], acc[0][0]);
        acc[0][1] = MF(aF[1], bF0[0], MF(aF[0], bF0[1], acc[0][1]));
        acc[0][2] = MF(aF[2], bF0[0], MF(aF[1], bF0[1], MF(aF[0], bF0[2], acc[0][2])));
        acc[0][3] = MF(aF[3], bF0[0], MF(aF[2], bF0[1], MF(aF[1], bF0[2], MF(aF[0], bF0[3], acc[0][3]))));
        acc[0][4] = MF(aF[4], bF0[0], MF(aF[3], bF0[1], MF(aF[2], bF0[2], MF(aF[1], bF0[3], MF(aF[0], bF0[4], acc[0][4])))));
        acc[1][0] = MF(aF[0], bF1[0], acc[1][0]);
        acc[1][1] = MF(aF[1], bF1[0], MF(aF[0], bF1[1], acc[1][1]));
        acc[1][2] = MF(aF[2], bF1[0], MF(aF[1], bF1[1], MF(aF[0], bF1[2], acc[1][2])));
        acc[1][3] = MF(aF[3], bF1[0], MF(aF[2], bF1[1], MF(aF[1], bF1[2], MF(aF[0], bF1[3], acc[1][3]))));
        acc[1][4] = MF(aF[4], bF1[0], MF(aF[3], bF1[1], MF(aF[2], bF1[2], MF(aF[1], bF1[3], MF(aF[0], bF1[4], acc[1][4])))));
        #undef MF
    }

    // ---- epilogue: exact f64 reconstruction + conv bias + BN, store f64 ----
    const int l15 = l & 15;
    const int rq  = l >> 4;
    #pragma unroll
    for (int s = 0; s < 2; ++s) {
        const int co = n0 + (cb2 + s) * 16 + l15;
        const double g   = (double)bn_gamma[co];
        const double be  = (double)bn_beta[co];
        const double mn  = (double)bn_mean[co];
        const double vr  = (double)bn_var[co];
        const double cb  = (double)conv_b[co];
        const double inv = 1.0 / sqrt(vr + 1e-5);
        #pragma unroll
        for (int r = 0; r < 4; ++r) {
            double v = (double)acc[s][0][r] * 0x1p-13
                     + (double)acc[s][1][r] * 0x1p-20
                     + (double)acc[s][2][r] * 0x1p-27
                     + (double)acc[s][3][r] * 0x1p-34
                     + (double)acc[s][4][r] * 0x1p-41;
            int m = m0 + rgM * 16 + rq * 4 + r;
            seq[(size_t)m * COUT + co] = g * (v + cb - mn) * inv + be;
        }
    }
}

// ---------------------------------------------------------------------------
// SNN scan v3 (unchanged from R5): 1 batch row per block, 512 threads.
// ---------------------------------------------------------------------------
__global__ __launch_bounds__(512, 4) void snn_scan_v3_kernel(
    const double* __restrict__ seq, const float* __restrict__ fc1wT,
    const float* __restrict__ fc1_b, const float* __restrict__ fc2_w,
    const float* __restrict__ fc2_b, const float* __restrict__ beta_enc,
    const float* __restrict__ beta_hid, const float* __restrict__ beta_out,
    float* __restrict__ out, int b_base)
{
    __shared__ int   list[COUT];
    __shared__ int   wcnt[8];
    __shared__ double red[8][2];

    const int tid  = threadIdx.x;
    const int lane = tid & 63;
    const int wave = tid >> 6;
    const int row  = blockIdx.x;
    const int brow = b_base + row;

    const double be  = clip01d((double)beta_enc[tid]);
    const double bh  = clip01d((double)beta_hid[tid]);
    const double f1b = (double)fc1_b[tid];
    const double w2a = (double)fc2_w[tid];
    const double w2b = (double)fc2_w[COUT + tid];

    double bo = 0.0, f2b = 0.0, om = 0.0;
    if (tid < 2) { bo = clip01d((double)beta_out[tid]); f2b = (double)fc2_b[tid]; }

    double em = 0.0, hm = 0.0;
    const double* sp = seq + (size_t)row * T_STEPS * COUT + tid;

    for (int t = 0; t < T_STEPS; ++t) {
        double inp = sp[(size_t)t * COUT];
        double e = be * em + inp - ((em > 1.0) ? 1.0 : 0.0);
        em = e;
        bool spike = (e > 1.0);

        unsigned long long mask = __ballot(spike);
        if (lane == 0) wcnt[wave] = __popcll(mask);
        __syncthreads();

        int base = 0, cnt = 0;
        #pragma unroll
        for (int w = 0; w < 8; ++w) {
            int v = wcnt[w];
            base += (w < wave) ? v : 0;
            cnt  += v;
        }
        if (spike) {
            int pos = base + __popcll(mask & ((1ull << lane) - 1ull));
            list[pos] = tid;
        }
        __syncthreads();

        double s0 = 0.0, s1 = 0.0, s2 = 0.0, s3 = 0.0;
        const float* fw = fc1wT + tid;
        int i = 0;
        for (; i + 4 <= cnt; i += 4) {
            int cA = list[i], cB = list[i + 1], cC = list[i + 2], cD = list[i + 3];
            float wA = fw[(size_t)cA * COUT];
            float wB = fw[(size_t)cB * COUT];
            float wC = fw[(size_t)cC * COUT];
            float wD = fw[(size_t)cD * COUT];
            s0 += (double)wA;
            s1 += (double)wB;
            s2 += (double)wC;
            s3 += (double)wD;
        }
        for (; i < cnt; ++i) s0 += (double)fw[(size_t)list[i] * COUT];
        double cur1 = ((s0 + s1) + (s2 + s3)) + f1b;

        double h = bh * hm + cur1 - ((hm > 1.0) ? 1.0 : 0.0);
        hm = h;
        double sh = (h > 1.0) ? 1.0 : 0.0;
        double p0 = sh * w2a;
        double p1 = sh * w2b;
        #pragma unroll
        for (int off = 32; off > 0; off >>= 1) {
            p0 += __shfl_down(p0, off);
            p1 += __shfl_down(p1, off);
        }
        if (lane == 0) { red[wave][0] = p0; red[wave][1] = p1; }
        __syncthreads();

        if (tid < 2) {
            double cur2 = f2b;
            #pragma unroll
            for (int w = 0; w < 8; ++w) cur2 += red[w][tid];
            double o = bo * om + cur2 - ((om > 1.0) ? 1.0 : 0.0);
            om = o;
            float so = (o > 1.0) ? 1.0f : 0.0f;
            int bidx = brow * 2 + tid;
            out[2048 + t * 2048 + bidx] = so;               // spk_rec
            out[2048 + 63488 + t * 2048 + bidx] = (float)o; // mem_rec
            if (t == T_STEPS - 1) out[bidx] = (float)o;     // final om
        }
    }
}

// ---------------------------------------------------------------------------
extern "C" void kernel_launch(void* const* d_in, const int* in_sizes, int n_in,
                              void* d_out, int out_size, void* d_ws, size_t ws_size,
                              hipStream_t stream)
{
    const float* x        = (const float*)d_in[0];
    const float* conv_w   = (const float*)d_in[1];
    const float* conv_b   = (const float*)d_in[2];
    const float* bn_gamma = (const float*)d_in[3];
    const float* bn_beta  = (const float*)d_in[4];
    const float* bn_mean  = (const float*)d_in[5];
    const float* bn_var   = (const float*)d_in[6];
    const float* fc1_w    = (const float*)d_in[7];
    const float* fc1_b    = (const float*)d_in[8];
    const float* fc2_w    = (const float*)d_in[9];
    const float* fc2_b    = (const float*)d_in[10];
    const float* beta_enc = (const float*)d_in[11];
    const float* beta_hid = (const float*)d_in[12];
    const float* beta_out = (const float*)d_in[13];
    float* out = (float*)d_out;

    // ws layout: Bd 5 MB | fc1wT 1 MB | seq 65 MB  (71.25 MB total)
    signed char* Bd    = (signed char*)d_ws;
    float*       fc1wT = (float*)((char*)d_ws + 5 * 1048576);
    double*      seq   = (double*)((char*)d_ws + 6 * 1048576);

    prep_fc1_kernel<<<1024, 256, 0, stream>>>(fc1_w, fc1wT);
    prep_bd_kernel<<<1024, 256, 0, stream>>>(conv_w, Bd);

    for (int chunk = 0; chunk < 2; ++chunk) {
        int b_base = chunk * BCHUNK;
        conv_bn_i8v2_kernel<<<(MCHUNK / 64) * (COUT / 64), 512, 0, stream>>>(
            x, Bd, conv_b, bn_gamma, bn_beta, bn_mean, bn_var, seq, b_base);
        snn_scan_v3_kernel<<<BCHUNK, 512, 0, stream>>>(
            seq, fc1wT, fc1_b, fc2_w, fc2_b, beta_enc, beta_hid, beta_out, out, b_base);
    }
}